// Round 14
// baseline (225.906 us; speedup 1.0000x reference)
//
#include <hip/hip_runtime.h>
#include <hip/hip_bf16.h>
#include <stdint.h>

// Correlation (FlowNet), md=4: out[b, di*9+dj, h, w] = sum_c x[b,c,h,w]*yp[b,c,h+di-4,w+dj-4] / 256
// R13: BARRIER-FREE, LDS-FREE gather formulation (packed-pair algebra of R11,
// per-wave 8-wide output => single N-phasing => fragments gathered straight
// from global). Every wave independent: no __shared__, no __syncthreads, no
// staging pipeline. Wave = (b, ph = h-pair 0..47, wq = 8-wide w tile 0..23).
// Per k-step (K=16): 1 x-frag (4 scalar loads) + 10 y-frags (40 scalar loads,
// per-lane predicated for pad) + 10 MFMAs into acc[10] (40 regs).

using f32x4 = __attribute__((ext_vector_type(4))) float;
using s16x4 = __attribute__((ext_vector_type(4))) short;

#define C_DIM 256
#define H_DIM 96
#define W_DIM 192
#define HWSZ  (H_DIM * W_DIM)
#define MD 4
#define KD 9
#define NPH 48             // h-pairs
#define NWQ 24             // 8-wide w tiles
#define NTHR 256

static __device__ __forceinline__ short bf16s(float f) {
  __bf16 h = (__bf16)f;                   // RNE
  short s; __builtin_memcpy(&s, &h, 2); return s;
}

__global__ __launch_bounds__(NTHR, 4)
void corr_gather(const float* __restrict__ xg, const float* __restrict__ yg,
                 float* __restrict__ outg) {
  const int bid = blockIdx.x;             // 2304 = 8 * 48 * 6
  const int b   = bid & 7;                // batch == XCD round-robin
  const int rem = bid >> 3;               // 0..287, ph fastest -> y-row L2/L1 reuse
  const int wqq = rem / NPH;              // 0..5
  const int ph  = rem % NPH;              // h-pair: rows 2ph, 2ph+1

  const int tid  = threadIdx.x;
  const int lane = tid & 63;
  const int wv   = tid >> 6;              // 0..3
  const int wq   = wqq * 4 + wv;          // 0..23 (4 block-waves share y rows)
  const int w0   = wq * 8;

  const int hi = lane >> 4;               // k-group: channels 4*hi+e
  const int lm = lane & 15;               // MFMA m (A) / n (B) coordinate

  // A-side decode (x): m = lm -> j = lm>>3 (h row), wp = lm&7 (w within tile)
  const int ja = lm >> 3;
  const int wp = lm & 7;
  const int ha = 2 * ph + ja;
  // x index base: c = 16t + 4hi + e -> xb + (16t+e)*HWSZ
  const uint32_t xb =
      ((uint32_t)(b * C_DIM + hi * 4) * H_DIM + ha) * W_DIM + (w0 + wp);

  // B-side decode (y): n = lm -> s = w0 - 4 + lm (per-lane, fixed)
  const int s = w0 - 4 + lm;
  const bool sok = (s >= 0) && (s < W_DIM);
  // y index: c = 16t + 4hi + e, row hg = 2ph - 4 + rp
  // idx = yb + (16t+e)*HWSZ + rp*W_DIM  (yb may be "negative row"; only used when valid)
  const int yb = ((b * C_DIM + hi * 4) * H_DIM + (2 * ph - MD)) * W_DIM + s;
  // row validity: hg = 2ph-4+rp in [0,96)
  unsigned rowok = 0;
#pragma unroll
  for (int rp = 0; rp < 10; ++rp) {
    const int hg = 2 * ph - MD + rp;
    if (sok && hg >= 0 && hg < H_DIM) rowok |= (1u << rp);
  }

  f32x4 acc[10];
#pragma unroll
  for (int rp = 0; rp < 10; ++rp) acc[rp] = f32x4{0.f, 0.f, 0.f, 0.f};

  for (int t = 0; t < 16; ++t) {          // K-steps of 16 channels
    const uint32_t cb = (uint32_t)t * 16 * HWSZ;

    // ---- A fragment: 4 scalar x loads (always in-bounds)
    s16x4 afr;
    {
      float a0 = xg[xb + cb];
      float a1 = xg[xb + cb + HWSZ];
      float a2 = xg[xb + cb + 2 * HWSZ];
      float a3 = xg[xb + cb + 3 * HWSZ];
      afr[0] = bf16s(a0); afr[1] = bf16s(a1);
      afr[2] = bf16s(a2); afr[3] = bf16s(a3);
    }

    // ---- 10 y fragments + MFMAs (independent acc -> compiler pipelines loads)
#pragma unroll
    for (int rp = 0; rp < 10; ++rp) {
      float y0 = 0.f, y1 = 0.f, y2 = 0.f, y3 = 0.f;
      if (rowok & (1u << rp)) {
        const uint32_t yi = (uint32_t)(yb + rp * W_DIM) + cb;
        y0 = yg[yi];
        y1 = yg[yi + HWSZ];
        y2 = yg[yi + 2 * HWSZ];
        y3 = yg[yi + 3 * HWSZ];
      }
      s16x4 bfr;
      bfr[0] = bf16s(y0); bfr[1] = bf16s(y1);
      bfr[2] = bf16s(y2); bfr[3] = bf16s(y3);
      acc[rp] = __builtin_amdgcn_mfma_f32_16x16x16bf16_1k(afr, bfr, acc[rp], 0, 0, 0);
    }
  }

  // ---- epilogue: D[m][n]: m = hi*4+rg -> (jm = m>>3, wm = m&7), n = lm.
  // di = rp - jm, dj = lm - wm; valid iff both in [0,9).
  const float scale = 1.f / 256.f;
#pragma unroll
  for (int rp = 0; rp < 10; ++rp) {
#pragma unroll
    for (int rg = 0; rg < 4; ++rg) {
      const int m  = hi * 4 + rg;
      const int jm = m >> 3;
      const int wm = m & 7;
      const int di = rp - jm;
      const int dj = lm - wm;
      if (0 <= di && di < KD && 0 <= dj && dj < KD) {
        outg[((b * (KD * KD) + di * KD + dj) * H_DIM + (2 * ph + jm)) * W_DIM
             + (w0 + wm)] = acc[rp][rg] * scale;
      }
    }
  }
}

extern "C" void kernel_launch(void* const* d_in, const int* in_sizes, int n_in,
                              void* d_out, int out_size, void* d_ws, size_t ws_size,
                              hipStream_t stream) {
  const float* x = (const float*)d_in[0];
  const float* y = (const float*)d_in[1];
  float* out = (float*)d_out;
  (void)in_sizes; (void)n_in; (void)d_ws; (void)ws_size; (void)out_size;

  const int grid = 8 * NPH * (NWQ / 4);   // 2304 blocks, 256 threads (4 waves)
  corr_gather<<<dim3(grid), dim3(NTHR), 0, stream>>>(x, y, out);
}

// Round 16
// 157.323 us; speedup vs baseline: 1.4359x; 1.4359x over previous
//
#include <hip/hip_runtime.h>
#include <hip/hip_bf16.h>
#include <stdint.h>

// Correlation (FlowNet), md=4: out[b, di*9+dj, h, w] = sum_c x[b,c,h,w]*yp[b,c,h+di-4,w+dj-4] / 256
// R15 = R14 with the abase bug fixed (+ 8*wh): global_load_lds DMA pipeline,
// f32 staged straight to LDS (no VGPR round-trip), double-buffered; chunk t+1
// DMA issued before compute(t), drained by the NEXT __syncthreads (a full
// compute phase later). Packed-pair formulation: wave = (pl, wh), 10 MFMAs/chunk,
// acc 40 regs. Block = 4 waves = 4 h-rows x 16 w. OOB staging lanes DMA from a
// zeroed region of d_ws (gload_lds cannot zero-fill).

using f32x4 = __attribute__((ext_vector_type(4))) float;
using s16x4 = __attribute__((ext_vector_type(4))) short;

#define AS1 __attribute__((address_space(1)))
#define AS3 __attribute__((address_space(3)))

#define C_DIM 256
#define H_DIM 96
#define W_DIM 192
#define HWSZ  (H_DIM * W_DIM)
#define MD 4
#define KD 9
#define NCHUNK 16            // chunks of 16 channels
#define NTHR 256
#define HB 24                // h blocks (4 rows each)
#define WB 12                // w blocks (16 cols each)
#define YUNITS 1344          // 12 rows x 16 c x 7 s-quads (16B units)
#define NUNITS 1600          // + 4 rows x 16 c x 4 s-quads of x
#define YBYTES (YUNITS * 16) // 21504
#define BUFSZ  (NUNITS * 16) // 25600
#define LDS_BYTES (2 * BUFSZ)

static __device__ __forceinline__ short bf16s(float f) {
  __bf16 h = (__bf16)f;                   // RNE
  short s; __builtin_memcpy(&s, &h, 2); return s;
}

__global__ __launch_bounds__(NTHR, 3)
void corr_gll(const float* __restrict__ xg, const float* __restrict__ yg,
              const float* __restrict__ zbuf, float* __restrict__ outg) {
  __shared__ __align__(16) char smem[LDS_BYTES];

  const int bid = blockIdx.x;             // 2304 = 8 * 24 * 12
  const int b   = bid & 7;                // batch == XCD round-robin
  const int rem = bid >> 3;               // hb fastest -> halo L2 reuse
  const int wb  = rem / HB;
  const int hb  = rem % HB;
  const int h0  = hb * 4;
  const int w0  = wb * 16;

  const int tid  = threadIdx.x;
  const int lane = tid & 63;
  const int wv   = tid >> 6;              // 0..3
  const int pl   = wv >> 1;               // pair: rows h0+2pl, h0+2pl+1
  const int wh   = wv & 1;                // w half: w0+8wh
  const int hi   = lane >> 4;
  const int lm   = lane & 15;

  // ---- staging decode, hoisted: per wave up to 7 gload_lds instrs.
  // unit u = (j*4+wv)*64 + lane. u<YUNITS: y (r = u/112, c = (u%112)/7, su = u%7);
  // else x (v = u-YUNITS: r8 = v>>6, c = (v>>2)&15, su = v&3).
  const float* gsrc[7];
  int jmax = 0;
#pragma unroll
  for (int j = 0; j < 7; ++j) {
    const int u = (j * 4 + wv) * 64 + lane;
    if ((j * 4 + wv) * 64 < NUNITS) {     // wave-uniform
      ++jmax;
      const float* p;
      if (u < YUNITS) {
        const int r  = u / 112;
        const int rm = u - r * 112;
        const int c  = rm / 7;
        const int su = rm - c * 7;
        const int hg = h0 - MD + r;
        const int sg = w0 - MD + 4 * su;
        const bool ok = (hg >= 0) && (hg < H_DIM) && (sg >= 0) && (sg + 3 < W_DIM);
        p = ok ? (yg + (((b * C_DIM + c) * H_DIM + hg) * W_DIM + sg)) : zbuf;
      } else {
        const int v  = u - YUNITS;        // 0..255
        const int r8 = v >> 6;
        const int c  = (v >> 2) & 15;
        const int su = v & 3;
        p = xg + (((b * C_DIM + c) * H_DIM + (h0 + r8)) * W_DIM + (w0 + 4 * su));
      }
      gsrc[j] = p;
    } else {
      gsrc[j] = zbuf;
    }
  }

  f32x4 acc[10];
#pragma unroll
  for (int rp = 0; rp < 10; ++rp) acc[rp] = f32x4{0.f, 0.f, 0.f, 0.f};

  // compute-phase index bases (dwords).
  // X region dword = r8*256 + c*16 + w_local (w_local 0..15):
  //   lane needs x at row 2pl+ja, c = 4hi+e, w_local = 8*wh + wp.  [R14 bug: +8*wh was missing]
  const int ja = lm >> 3, wp = lm & 7;
  const int abase = (2 * pl + ja) * 256 + (4 * hi) * 16 + 8 * wh + wp;
  // Y region dword = r*448 + c*28 + sl, sl = s-(w0-4):
  //   lane needs y at row 2pl+rp, c = 4hi+e, sl = lm + 8wh.
  const int sl = lm + 8 * wh;
  const int bbase = (2 * pl) * 448 + (4 * hi) * 28 + sl;

  AS3 char* lds = (AS3 char*)smem;

#define STAGE(t, boff) { \
    const uint32_t co = (uint32_t)(t) * 16 * HWSZ; \
    _Pragma("unroll") \
    for (int j = 0; j < 7; ++j) { \
      if (j < jmax) { \
        const float* p = gsrc[j]; \
        const float* pc = (p == zbuf) ? p : (p + co); \
        __builtin_amdgcn_global_load_lds((const AS1 void*)pc, \
            (AS3 void*)(lds + (boff) + (uint32_t)(j * 4 + wv) * 1024), 16, 0, 0); \
      } \
    } }

  // ---- prologue: stage chunk 0 into buf0, drain, sync
  STAGE(0, 0)
  __syncthreads();                        // drains vmcnt -> buf0 ready

  for (int t = 0; t < NCHUNK; ++t) {
    // ---- issue chunk t+1 DMA now (no VGPRs held; drained at the NEXT barrier,
    // a full compute phase after issue)
    if (t + 1 < NCHUNK) {
      const uint32_t wo = (uint32_t)((t + 1) & 1) * BUFSZ;
      STAGE(t + 1, wo)
    }

    // ---- compute chunk t from buf[t&1] (cvt at fragment-read time)
    const float* Y = (const float*)(smem + (t & 1) * BUFSZ);
    const float* X = (const float*)(smem + (t & 1) * BUFSZ + YBYTES);

    s16x4 afr;
    {
      float a0 = X[abase], a1 = X[abase + 16], a2 = X[abase + 32], a3 = X[abase + 48];
      afr[0] = bf16s(a0); afr[1] = bf16s(a1); afr[2] = bf16s(a2); afr[3] = bf16s(a3);
    }
#pragma unroll
    for (int rp = 0; rp < 10; ++rp) {
      const int o = bbase + rp * 448;
      float y0 = Y[o], y1 = Y[o + 28], y2 = Y[o + 56], y3 = Y[o + 84];
      s16x4 bfr;
      bfr[0] = bf16s(y0); bfr[1] = bf16s(y1); bfr[2] = bf16s(y2); bfr[3] = bf16s(y3);
      acc[rp] = __builtin_amdgcn_mfma_f32_16x16x16bf16_1k(afr, bfr, acc[rp], 0, 0, 0);
    }

    // ---- one barrier per chunk: drains this wave's ds reads AND the t+1 DMA,
    // publishing buf[(t+1)&1] to all waves.
    __syncthreads();
  }

  // ---- epilogue (R13-verified algebra): m = hi*4+rg -> (jm, wm); n = lm.
  // di = rp - jm, dj = lm - wm; h = h0 + 2pl + jm, w = w0 + 8wh + wm.
  const float scale = 1.f / 256.f;
#pragma unroll
  for (int rp = 0; rp < 10; ++rp) {
#pragma unroll
    for (int rg = 0; rg < 4; ++rg) {
      const int m  = hi * 4 + rg;
      const int jm = m >> 3;
      const int wm = m & 7;
      const int di = rp - jm;
      const int dj = lm - wm;
      if (0 <= di && di < KD && 0 <= dj && dj < KD) {
        outg[((b * (KD * KD) + di * KD + dj) * H_DIM + (h0 + 2 * pl + jm)) * W_DIM
             + (w0 + 8 * wh + wm)] = acc[rp][rg] * scale;
      }
    }
  }
}

extern "C" void kernel_launch(void* const* d_in, const int* in_sizes, int n_in,
                              void* d_out, int out_size, void* d_ws, size_t ws_size,
                              hipStream_t stream) {
  const float* x = (const float*)d_in[0];
  const float* y = (const float*)d_in[1];
  float* out = (float*)d_out;
  (void)in_sizes; (void)n_in; (void)out_size; (void)ws_size;

  // zero 256B of workspace: OOB staging lanes DMA from here
  hipMemsetAsync(d_ws, 0, 256, stream);

  const int grid = 8 * HB * WB;           // 2304 blocks, 256 threads (4 waves)
  corr_gll<<<dim3(grid), dim3(NTHR), 0, stream>>>(x, y, (const float*)d_ws, out);
}

// Round 17
// 147.479 us; speedup vs baseline: 1.5318x; 1.0667x over previous
//
#include <hip/hip_runtime.h>
#include <hip/hip_bf16.h>
#include <stdint.h>

// Correlation (FlowNet), md=4: out[b, di*9+dj, h, w] = sum_c x[b,c,h,w]*yp[b,c,h+di-4,w+dj-4] / 256
// R16 = R9 champion (HR=8, CHUNK=32, SUB_B=128, x-in-LDS, single-buffer) with
// ONE change: dispatch order wt-FASTEST (was hq-fastest). The 12 w-tiles sharing
// each 768B y-row / 2KB DRAM page are now dispatch-adjacent (and same-XCD, being
// 8 bids apart) -> co-resident page sharing: full DRAM row-buffer utilization
// instead of 96B-per-page scatter. Tests the page-efficiency-cap hypothesis.

using f32x4 = __attribute__((ext_vector_type(4))) float;
using s16x4 = __attribute__((ext_vector_type(4))) short;
using u16x4 = __attribute__((ext_vector_type(4))) unsigned short;

#define C_DIM 256
#define H_DIM 96
#define W_DIM 192
#define HWSZ  (H_DIM * W_DIM)
#define MD 4
#define KD 9
#define CHUNK 32
#define HR 8
#define NTHR 512
#define WTILES 12          // 192/16
#define HQ 12              // 96/8
#define SUB_B 128          // [4c][16s] bf16 subtile = 128B, aligned (tr native)
#define YROW_B (16 * SUB_B)   // 2 t * 8 cg subtiles = 2048B per y row
#define XROW_B (8 * SUB_B)    // t=0 only = 1024B per x row
#define XBASE  (16 * YROW_B)  // 32768
#define LDS_BYTES (XBASE + 8 * XROW_B)   // 40960

static __device__ __forceinline__ unsigned short bf16b(float f) {
  __bf16 h = (__bf16)f;                   // RNE
  unsigned short s; __builtin_memcpy(&s, &h, 2); return s;
}

// per-lane: reads column (l&15) of the [4c][16s] bf16 subtile at its address
static __device__ __forceinline__ s16x4 tr16(uint32_t addr) {
  s16x4 d;
  asm volatile("ds_read_b64_tr_b16 %0, %1" : "=v"(d) : "v"(addr));
  return d;
}

__global__ __launch_bounds__(NTHR, 4)
void corr_mfma(const float* __restrict__ xg, const float* __restrict__ yg,
               float* __restrict__ outg) {
  __shared__ __align__(16) char smem[LDS_BYTES];

  const int bid = blockIdx.x;             // 1152 = 8 * 144
  const int b   = bid & 7;                // batch == XCD (round-robin dispatch)
  const int rem = bid >> 3;               // 0..143, wt fastest -> DRAM page sharing
  const int hq  = rem / WTILES;
  const int wt  = rem - hq * WTILES;
  const int w0  = wt * 16;
  const int h0  = hq * HR;

  const int tid  = threadIdx.x;
  const int lane = tid & 63;
  const int wv   = tid >> 6;              // wave id 0..7 -> output row h0+wv
  const int hi   = lane >> 4;
  const int lm   = lane & 15;

  const uint32_t sbase = (uint32_t)(uintptr_t)&smem[0];  // LDS aperture 4GB-aligned

  // ---- staging decode, hoisted. i<6: y quads (16 rows x 32c x 6q); i 6,7: x (8 x 32c x 4q)
  uint32_t goffY[6], loffY[6], goffX[2], loffX[2];
  uint32_t vmaskY = 0;
#pragma unroll
  for (int i = 0; i < 6; ++i) {
    const int qid = i * NTHR + tid;
    const int q = qid % 6;
    const int c = (qid / 6) % CHUNK;
    const int r = qid / 192;              // y row 0..15 -> h0+r-4
    const int hg = h0 + r - MD;
    const int sg = w0 - MD + 4 * q;       // 4-aligned -> OOB is whole-quad only
    const bool ok = (hg >= 0) && (hg < H_DIM) && (sg >= 0) && (sg < W_DIM);
    if (ok) vmaskY |= (1u << i);
    goffY[i] = ok ? (uint32_t)(((b * C_DIM + c) * H_DIM + hg) * W_DIM + sg) : 0u;
    const int s = 4 * q;                  // local s 0..20
    loffY[i] = r * YROW_B + (s >> 4) * (8 * SUB_B) + (c >> 2) * SUB_B
             + (c & 3) * 32 + (s & 15) * 2;
  }
#pragma unroll
  for (int i = 0; i < 2; ++i) {
    const int qid = i * NTHR + tid;
    const int q = qid & 3;                // x staged without w-halo: s = w-w0
    const int c = (qid >> 2) & 31;
    const int r = qid >> 7;               // 0..7 -> h0+r
    goffX[i] = (uint32_t)(((b * C_DIM + c) * H_DIM + (h0 + r)) * W_DIM + (w0 + 4 * q));
    loffX[i] = XBASE + r * XROW_B + (c >> 2) * SUB_B + (c & 3) * 32 + 8 * q;
  }

  f32x4 acc[KD][2];
#pragma unroll
  for (int di = 0; di < KD; ++di) {
    acc[di][0] = f32x4{0.f, 0.f, 0.f, 0.f};
    acc[di][1] = f32x4{0.f, 0.f, 0.f, 0.f};
  }

  // fragment base addresses: subtile cg = kh*4+hi holds channels kh*16+hi*4..+3
  const uint32_t abase = sbase + XBASE + wv * XROW_B + hi * SUB_B + lm * 8;
  const uint32_t bbase = sbase + wv * YROW_B + hi * SUB_B + lm * 8;

  for (int c0 = 0; c0 < C_DIM; c0 += CHUNK) {
    // ---- global loads + convert (before barrier: overlaps other waves' compute)
    u16x4 wbuf[8];
#pragma unroll
    for (int i = 0; i < 6; ++i) {
      float4 v = make_float4(0.f, 0.f, 0.f, 0.f);
      if (vmaskY & (1u << i)) v = *(const float4*)(yg + goffY[i] + (uint32_t)c0 * HWSZ);
      wbuf[i] = u16x4{bf16b(v.x), bf16b(v.y), bf16b(v.z), bf16b(v.w)};
    }
#pragma unroll
    for (int i = 0; i < 2; ++i) {
      float4 v = *(const float4*)(xg + goffX[i] + (uint32_t)c0 * HWSZ);
      wbuf[6 + i] = u16x4{bf16b(v.x), bf16b(v.y), bf16b(v.z), bf16b(v.w)};
    }

    __syncthreads();                      // previous chunk's LDS reads done
#pragma unroll
    for (int i = 0; i < 6; ++i) *(u16x4*)(smem + loffY[i]) = wbuf[i];
#pragma unroll
    for (int i = 0; i < 2; ++i) *(u16x4*)(smem + loffX[i]) = wbuf[6 + i];
    __syncthreads();

    // ---- A fragments: x row (LDS row wv), col w0+lm
    s16x4 afr0 = tr16(abase);
    s16x4 afr1 = tr16(abase + 4 * SUB_B);
    s16x4 bc0 = tr16(bbase);
    s16x4 bc1 = tr16(bbase + 4 * SUB_B);
    s16x4 bc2 = tr16(bbase + 8 * SUB_B);
    s16x4 bc3 = tr16(bbase + 12 * SUB_B);
#pragma unroll
    for (int di = 0; di < KD; ++di) {
      s16x4 bn0, bn1, bn2, bn3;
      if (di < 8) {
        const uint32_t bb = bbase + (uint32_t)(di + 1) * YROW_B;  // y row wv+di+1
        bn0 = tr16(bb);
        bn1 = tr16(bb + 4 * SUB_B);
        bn2 = tr16(bb + 8 * SUB_B);
        bn3 = tr16(bb + 12 * SUB_B);
        asm volatile("s_waitcnt lgkmcnt(4)" ::: "memory");  // cur frags (+A) done
      } else {
        asm volatile("s_waitcnt lgkmcnt(0)" ::: "memory");
      }
      __builtin_amdgcn_sched_barrier(0);  // rule #18: don't hoist MFMA past waitcnt
      acc[di][0] = __builtin_amdgcn_mfma_f32_16x16x16bf16_1k(afr0, bc0, acc[di][0], 0, 0, 0);
      acc[di][0] = __builtin_amdgcn_mfma_f32_16x16x16bf16_1k(afr1, bc1, acc[di][0], 0, 0, 0);
      acc[di][1] = __builtin_amdgcn_mfma_f32_16x16x16bf16_1k(afr0, bc2, acc[di][1], 0, 0, 0);
      acc[di][1] = __builtin_amdgcn_mfma_f32_16x16x16bf16_1k(afr1, bc3, acc[di][1], 0, 0, 0);
      if (di < 8) { bc0 = bn0; bc1 = bn1; bc2 = bn2; bc3 = bn3; }
    }
  }

  // ---- epilogue: D[m][n]: n=lm, m=hi*4+rg (verified). dj = t*16 + lm - m.
  const int h = h0 + wv;
  const float scale = 1.f / 256.f;
#pragma unroll
  for (int di = 0; di < KD; ++di) {
#pragma unroll
    for (int t = 0; t < 2; ++t) {
#pragma unroll
      for (int rg = 0; rg < 4; ++rg) {
        const int m = hi * 4 + rg;
        const int dj = t * 16 + lm - m;
        if (0 <= dj && dj <= 8) {
          outg[((b * (KD * KD) + di * KD + dj) * H_DIM + h) * W_DIM + w0 + m] =
              acc[di][t][rg] * scale;
        }
      }
    }
  }
}

extern "C" void kernel_launch(void* const* d_in, const int* in_sizes, int n_in,
                              void* d_out, int out_size, void* d_ws, size_t ws_size,
                              hipStream_t stream) {
  const float* x = (const float*)d_in[0];
  const float* y = (const float*)d_in[1];
  float* out = (float*)d_out;
  (void)in_sizes; (void)n_in; (void)d_ws; (void)ws_size; (void)out_size;

  const int grid = 8 * HQ * WTILES;       // 1152 blocks, 512 threads
  corr_mfma<<<dim3(grid), dim3(NTHR), 0, stream>>>(x, y, out);
}